// Round 4
// baseline (679.740 us; speedup 1.0000x reference)
//
#include <hip/hip_runtime.h>
#include <hip/hip_bf16.h>

// Problem constants (from reference setup_inputs)
constexpr int K    = 64;
constexpr int N    = 1024;
constexpr int DIN  = 16;
constexpr int H1   = 4;
constexpr int DOUT = 8;
constexpr int FC1  = 54;

#define ALPHA_F   (0.01f)
#define LOG2E_F   (1.4426950408889634f)

typedef unsigned int uint;
typedef short  bf16x8 __attribute__((ext_vector_type(8)));
typedef float  f32x4  __attribute__((ext_vector_type(4)));

__device__ inline float fast_exp2(float x) {
#if __has_builtin(__builtin_amdgcn_exp2f)
    return __builtin_amdgcn_exp2f(x);      // raw v_exp_f32
#else
    return __expf(x * 0.6931471805599453f);
#endif
}

// packed bf16 pair (RNE) -> uint (lo=a, hi=b); v_cvt_pk_bf16_f32 on gfx950
__device__ inline uint pk_bf16(float a, float b) {
    union { __hip_bfloat162 h; uint u; } v;
    v.h = __float22bfloat162_rn(make_float2(a, b));
    return v.u;
}

// ---------------------------------------------------------------------------
// Grid barrier: regular-launch-safe (no cooperative API, graph-capture OK).
// Persistent __device__ counters (zero at module load, NOT in poisoned ws).
// Ticket scheme: target=(t/64+1)*64 per 64-block shard -> self-consistent
// across graph replays with no reset.  8 shards, 128 B apart, cut same-line
// RMW serialization.  __threadfence() = agent-scope fence: emits the gfx950
// L2 writeback/invalidate needed for cross-XCD visibility of plain stores.
// Deadlock-safe by construction: __launch_bounds__(512,4) => VGPR<=128 =>
// 2 blocks/CU x 256 CU = 512 co-resident blocks = the whole grid.
// ---------------------------------------------------------------------------
__device__ unsigned long long g_bar[3][8][16];   // [barrier][shard][pad 128B]

__device__ __forceinline__ void grid_barrier(int b) {
    __threadfence();                             // release our plain stores
    __syncthreads();
    if (threadIdx.x == 0) {
        const int s = blockIdx.x & 7;
        unsigned long long t = __hip_atomic_fetch_add(
            &g_bar[b][s][0], 1ull, __ATOMIC_SEQ_CST, __HIP_MEMORY_SCOPE_AGENT);
        const unsigned long long tgt = (t >> 6) * 64ull + 64ull;  // (t/64+1)*64
        #pragma unroll 1
        for (int ss = 0; ss < 8; ss++) {
            while (__hip_atomic_load(&g_bar[b][ss][0],
                       __ATOMIC_ACQUIRE, __HIP_MEMORY_SCOPE_AGENT) < tgt) {
                __builtin_amdgcn_s_sleep(1);
            }
        }
    }
    __syncthreads();
    __threadfence();                             // acquire for all threads
}

// ---------------------------------------------------------------------------
// B-fragment table layout (consumed by mfma_f32_16x16x32_bf16):
//   HB[k][c][lane] : uint4;  lane=(q=lane>>4, n=lane&15)
//   dword t packs rows j=c*32+q*8+2t, +2t+1 of column n:
//   n<F -> bf16(h[j][n]); n==F -> 1.0 (denominator column); n>F -> 0.
// ---------------------------------------------------------------------------

struct SharedBufs {
    float F2s[1024];       // f2[k] (4 KB)
    float XPa[8][16][5];   // FUSE: attn output xo
    float XPb[8][16][9];   // FUSE: projected hv / !FUSE: xo tile
    float YPs[8][64];      // !FUSE: per-wave fc1 partials
    float hrow[128 * 4];   // P0 proj row-stage
    float ybuf[FC1];       // P3 fc1 activations
};  // ~15.7 KB; 2 blocks/CU -> 31 KB/CU, far under 160 KB

// ---------------------------------------------------------------------------
// Attention phase (instruction-identical main loop to the verified R2 kernel).
// FUSE (layer 1): epilogue computes layer-2 projection AND writes the HB2
// fragment table directly (wave-local LDS transpose), plus f12/f22.
// !FUSE (layer 2): epilogue computes per-wave fc1 partials over its 16x8
// output tile; block-reduces; writes race-free slot yp[blockIdx.x*64+c].
// ---------------------------------------------------------------------------
template <int F, bool FUSE>
__device__ __forceinline__ void attn_phase(
        const unsigned long long* __restrict__ maskM,  // [N][16] row-major
        const uint4* __restrict__ HBin,  // [K][32][64] B-frags
        const float* __restrict__ f1,    // [K,N]  (x log2e)
        const float* __restrict__ f2,    // [K,N]  (x log2e)
        const float* __restrict__ W2,    // [4,8]  (FUSE only)
        const float* __restrict__ a2,    // [16]   (FUSE only)
        const float* __restrict__ fc1w,  // [8192,54] (!FUSE only)
        uint4* __restrict__ HBout,       // FUSE: HB2 table
        float* __restrict__ yp,          // !FUSE: fc1 partial slots [512][64]
        float* __restrict__ o_f1,        // FUSE: f12 (x log2e)
        float* __restrict__ o_f2,        // FUSE: f22 (x log2e)
        SharedBufs& S) {
    const int tid  = threadIdx.x;
    const int lane = tid & 63;
    const int wv   = tid >> 6;
    const int quad = lane >> 4;
    const int n16  = lane & 15;
    const int k    = blockIdx.x >> 3;

    if (tid < 256)
        ((float4*)S.F2s)[tid] = ((const float4*)(f2 + k * N))[tid];
    __syncthreads();

    const int itile = (blockIdx.x & 7) * 8 + wv;     // 0..63
    const int ibase = itile * 16;
    const int irow  = ibase + n16;                   // this lane's P row
    const float f1v = f1[k * N + irow];
    const uint4* mrow = (const uint4*)((const char*)maskM + (size_t)irow * 128);
    const uint4* HBk  = HBin + (size_t)k * 2048;

    f32x4 acc = {0.f, 0.f, 0.f, 0.f};
    union { bf16x8 v; uint u[4]; } af;
    union { bf16x8 v; uint4 q; }  bfrag;

    #pragma unroll 2
    for (int g = 0; g < 8; g++) {
        const uint4 Mg = mrow[g];                    // 4 chunks of mask bits
        #pragma unroll
        for (int cc = 0; cc < 4; cc++) {
            const int c = g * 4 + cc;
            const uint mdw = (cc == 0) ? Mg.x : (cc == 1) ? Mg.y
                           : (cc == 2) ? Mg.z : Mg.w;
            const uint mb  = (mdw >> (quad * 8)) & 0xffu;  // 8 bits, this lane
            float4 fa = *(const float4*)(S.F2s + c * 32 + quad * 8);
            float4 fb = *(const float4*)(S.F2s + c * 32 + quad * 8 + 4);
            bfrag.q = HBk[c * 64 + lane];            // coalesced VMEM (L2)
            float f2e[8] = {fa.x, fa.y, fa.z, fa.w, fb.x, fb.y, fb.z, fb.w};
            float pv[8];
            #pragma unroll
            for (int jj = 0; jj < 8; jj++) {
                float x = f1v + f2e[jj];
                float e = fmaxf(x, ALPHA_F * x);     // leaky (log2-scaled)
                float p = fast_exp2(e);
                pv[jj] = (mb & (1u << jj)) ? p : 0.f;  // mask -> exact 0
            }
            #pragma unroll
            for (int pr = 0; pr < 4; pr++)
                af.u[pr] = pk_bf16(pv[2 * pr], pv[2 * pr + 1]);
            acc = __builtin_amdgcn_mfma_f32_16x16x32_bf16(af.v, bfrag.v, acc, 0, 0, 0);
        }
    }

    // ---- epilogue: C[m][n]: n=lane&15, m=quad*4+reg; denom in col n==F ----
    #pragma unroll
    for (int r = 0; r < 4; r++) {
        float den = __shfl(acc[r], (lane & 48) + F);
        float inv = (den > 0.f) ? 1.f / den : 0.f;
        float xo  = fmaxf(acc[r] * inv, 0.f);        // relu
        int m = quad * 4 + r;
        if constexpr (FUSE) {
            if (n16 < F) S.XPa[wv][m][n16] = xo;
        } else {
            if (n16 < F) S.XPb[wv][m][n16] = xo;     // wave-local stage
        }
    }

    if constexpr (FUSE) {
        __syncthreads();
        if (lane < 16) {
            const int m = lane;
            float x0 = S.XPa[wv][m][0], x1 = S.XPa[wv][m][1];
            float x2v = S.XPa[wv][m][2], x3 = S.XPa[wv][m][3];
            float hv[DOUT];
            #pragma unroll
            for (int f = 0; f < DOUT; f++) {
                hv[f] = x0 * W2[f]      + x1 * W2[8 + f]
                      + x2v * W2[16 + f] + x3 * W2[24 + f];
            }
            float t1 = 0.f, t2 = 0.f;
            #pragma unroll
            for (int f = 0; f < DOUT; f++) { t1 += hv[f] * a2[f]; t2 += hv[f] * a2[DOUT + f]; }
            const int row = k * N + ibase + m;
            o_f1[row] = t1 * LOG2E_F;
            o_f2[row] = t2 * LOG2E_F;
            #pragma unroll
            for (int f = 0; f < DOUT; f++) S.XPb[wv][m][f] = hv[f];
        }
        __syncthreads();
        if (lane < 32) {
            const int c2    = ibase >> 5;
            const int qhalf = (ibase >> 4) & 1;
            const int ql    = lane >> 4;
            const int n     = lane & 15;
            const int q     = qhalf * 2 + ql;
            uint4 dw;
            if (n < DOUT) {
                dw.x = pk_bf16(S.XPb[wv][ql * 8 + 0][n], S.XPb[wv][ql * 8 + 1][n]);
                dw.y = pk_bf16(S.XPb[wv][ql * 8 + 2][n], S.XPb[wv][ql * 8 + 3][n]);
                dw.z = pk_bf16(S.XPb[wv][ql * 8 + 4][n], S.XPb[wv][ql * 8 + 5][n]);
                dw.w = pk_bf16(S.XPb[wv][ql * 8 + 6][n], S.XPb[wv][ql * 8 + 7][n]);
            } else if (n == DOUT) {
                dw = make_uint4(0x3f803f80u, 0x3f803f80u, 0x3f803f80u, 0x3f803f80u);
            } else {
                dw = make_uint4(0u, 0u, 0u, 0u);
            }
            HBout[(size_t)k * 2048 + c2 * 64 + q * 16 + n] = dw;
        }
    } else {
        // ---- fused fc1: per-wave partial over this wave's 128 x2-columns ----
        // x2[k][m] for m = ibase*8 + mm, mm = lr*8 + f, lives in XPb[wv][lr][f]
        // (wave-local LDS: same wave wrote it, lgkmcnt ordering suffices).
        const int ceff = (lane < FC1) ? lane : 0;    // c = lane (54 active)
        const float* wb = fc1w + (size_t)ibase * DOUT * FC1;
        float pacc = 0.f;
        #pragma unroll 8
        for (int mm = 0; mm < 128; mm++) {
            float xv = S.XPb[wv][mm >> 3][mm & 7];   // wave-uniform broadcast
            pacc = fmaf(xv, wb[(size_t)mm * FC1 + ceff], pacc);
        }
        S.YPs[wv][lane] = pacc;
        __syncthreads();
        if (tid < 64) {
            float s = 0.f;
            #pragma unroll
            for (int w = 0; w < 8; w++) s += S.YPs[w][tid];
            yp[blockIdx.x * 64 + tid] = s;           // race-free slot write
        }
    }
}

// ---------------------------------------------------------------------------
// Mega kernel (regular launch + hand-rolled grid barrier):
// 512 blocks x 512 threads (= exactly 2 co-resident blocks/CU), 4 phases.
//  P0: mask pack (4 units/wave over all blocks) + gat1 proj of 128 rows/block
//      -> HB1 frags + f11/f21
//  P1: attn layer 1 (FUSE)  -> HB2 + f12/f22
//  P2: attn layer 2 + fused fc1 partials -> yp slots
//  P3: blocks 0..127: reduce yp + bias + relu -> out GEMV
// ---------------------------------------------------------------------------
__global__ __launch_bounds__(512, 4) void mega_kernel(
        const int* __restrict__ adj, unsigned long long* __restrict__ maskM,
        const float* __restrict__ X, const float* __restrict__ W1,
        const float* __restrict__ a1,
        uint4* __restrict__ HB1, float* __restrict__ f11, float* __restrict__ f21,
        const float* __restrict__ W2, const float* __restrict__ a2,
        const float* __restrict__ fc1w,
        uint4* __restrict__ HB2, float* __restrict__ f12, float* __restrict__ f22,
        float* __restrict__ yp,
        const float* __restrict__ fc1b, const float* __restrict__ outw,
        const float* __restrict__ outb, float* __restrict__ out) {
    __shared__ SharedBufs S;
    const int tid  = threadIdx.x;
    const int lane = tid & 63;
    const int wv   = tid >> 6;
    const int bid  = blockIdx.x;

    // ---- P0a: adjacency mask pack (16384 (i,jw) units; 4 per wave) ----
    {
        int g = bid * 8 + wv;              // 0..4095
        #pragma unroll
        for (int uu = 0; uu < 4; uu++) {
            int u = g * 4 + uu;            // 0..16383
            int jw = u >> 10;              // 0..15
            int i  = u & 1023;
            int v = adj[i * N + (jw << 6) + lane];    // coalesced 256B/wave
            unsigned long long m = __ballot(v > 0);   // bit lane = adj>0
            if (lane == 0) maskM[i * 16 + jw] = m;    // row-major
        }
    }

    // ---- P0b: gat1 proj, 128 rows per block -> f11/f21 + HB1 frags ----
    {
        const int k  = bid >> 3;
        const int j0 = (bid & 7) << 7;     // 0,128,...,896
        if (tid < 128) {
            const int idx = k * N + j0 + tid;
            const float4* x4 = (const float4*)(X + (size_t)idx * DIN);
            float hv_[H1] = {0.f, 0.f, 0.f, 0.f};
            #pragma unroll
            for (int q = 0; q < 4; q++) {
                float4 xv = x4[q];
                #pragma unroll
                for (int f = 0; f < H1; f++) {
                    hv_[f] += xv.x * W1[(q * 4 + 0) * H1 + f] + xv.y * W1[(q * 4 + 1) * H1 + f]
                            + xv.z * W1[(q * 4 + 2) * H1 + f] + xv.w * W1[(q * 4 + 3) * H1 + f];
                }
            }
            float s1 = 0.f, s2 = 0.f;
            #pragma unroll
            for (int f = 0; f < H1; f++) { s1 += hv_[f] * a1[f]; s2 += hv_[f] * a1[H1 + f]; }
            f11[idx] = s1 * LOG2E_F;
            f21[idx] = s2 * LOG2E_F;
            #pragma unroll
            for (int f = 0; f < H1; f++) S.hrow[tid * 4 + f] = hv_[f];
        }
        __syncthreads();
        if (tid < 256) {                   // 4 chunk-locals x 64 lanes
            int cl = tid >> 6, l = tid & 63, q = (l >> 4), n = l & 15;
            uint4 dw;
            if (n < H1) {
                const float* hp = S.hrow + (cl * 32 + q * 8) * 4 + n;
                dw.x = pk_bf16(hp[0],  hp[4]);
                dw.y = pk_bf16(hp[8],  hp[12]);
                dw.z = pk_bf16(hp[16], hp[20]);
                dw.w = pk_bf16(hp[24], hp[28]);
            } else if (n == H1) {
                dw = make_uint4(0x3f803f80u, 0x3f803f80u, 0x3f803f80u, 0x3f803f80u);
            } else {
                dw = make_uint4(0u, 0u, 0u, 0u);
            }
            HB1[(size_t)k * 2048 + ((j0 >> 5) + cl) * 64 + l] = dw;
        }
    }

    grid_barrier(0);

    // ---- P1: attention layer 1 (FUSE) ----
    attn_phase<H1, true>(maskM, HB1, f11, f21, W2, a2, nullptr,
                         HB2, nullptr, f12, f22, S);

    grid_barrier(1);

    // ---- P2: attention layer 2 + fused fc1 partials ----
    attn_phase<DOUT, false>(maskM, HB2, f12, f22, nullptr, nullptr, fc1w,
                            nullptr, yp, nullptr, nullptr, S);

    grid_barrier(2);

    // ---- P3: fc2 on blocks 0..127 (k = bid>>1, n-half = bid&1) ----
    if (bid < 128) {
        const int k  = bid >> 1;
        const int nh = bid & 1;
        if (tid < FC1) {
            float s = fc1b[tid];
            #pragma unroll
            for (int sl = 0; sl < 8; sl++) s += yp[((k << 3) + sl) * 64 + tid];
            S.ybuf[tid] = fmaxf(s, 0.f);   // bias + relu
        }
        __syncthreads();
        const int n = (nh << 9) + tid;     // 0..1023
        float s = outb[n];
        #pragma unroll 6
        for (int cc = 0; cc < FC1; cc++)
            s += S.ybuf[cc] * outw[(size_t)cc * N + n];
        out[(size_t)k * N + n] = s;
    }
}

// ---------------------------------------------------------------------------
extern "C" void kernel_launch(void* const* d_in, const int* in_sizes, int n_in,
                              void* d_out, int out_size, void* d_ws, size_t ws_size,
                              hipStream_t stream) {
    const float* X     = (const float*)d_in[0];
    const int*   adj   = (const int*)  d_in[1];
    const float* W1    = (const float*)d_in[2];
    const float* a1    = (const float*)d_in[3];
    const float* W2    = (const float*)d_in[4];
    const float* a2    = (const float*)d_in[5];
    const float* fc1w  = (const float*)d_in[6];
    const float* fc1b  = (const float*)d_in[7];
    const float* outw  = (const float*)d_in[8];
    const float* outb  = (const float*)d_in[9];
    float* out = (float*)d_out;

    // Workspace layout (floats); ~5.5 MB total
    float* ws  = (float*)d_ws;
    float* f11 = ws;                       // 65536
    float* f21 = f11 + 65536;              // 65536
    float* f12 = f21 + 65536;              // 65536
    float* f22 = f12 + 65536;              // 65536
    float* yp  = f22 + 65536;              // 32768 (512 slots x 64)
    unsigned long long* mM = (unsigned long long*)(yp + 32768);    // 16384 u64
    uint4* HB1 = (uint4*)(yp + 32768 + 32768);                     // 131072 u4
    uint4* HB2 = HB1 + 131072;                                     // 131072 u4

    mega_kernel<<<dim3(512), dim3(512), 0, stream>>>(
        adj, mM, X, W1, a1, HB1, f11, f21, W2, a2, fc1w,
        HB2, f12, f22, yp, fc1b, outw, outb, out);
}

// Round 6
// 184.356 us; speedup vs baseline: 3.6871x; 3.6871x over previous
//
#include <hip/hip_runtime.h>
#include <hip/hip_bf16.h>

// Problem constants (from reference setup_inputs)
constexpr int K    = 64;
constexpr int N    = 1024;
constexpr int DIN  = 16;
constexpr int H1   = 4;
constexpr int DOUT = 8;
constexpr int FC1  = 54;

#define ALPHA_F   (0.01f)
#define LOG2E_F   (1.4426950408889634f)

typedef unsigned int uint;
typedef short  bf16x8 __attribute__((ext_vector_type(8)));
typedef float  f32x4  __attribute__((ext_vector_type(4)));

__device__ inline float fast_exp2(float x) {
#if __has_builtin(__builtin_amdgcn_exp2f)
    return __builtin_amdgcn_exp2f(x);      // raw v_exp_f32
#else
    return __expf(x * 0.6931471805599453f);
#endif
}

// packed bf16 pair (RNE) -> uint (lo=a, hi=b); v_cvt_pk_bf16_f32 on gfx950
__device__ inline uint pk_bf16(float a, float b) {
    union { __hip_bfloat162 h; uint u; } v;
    v.h = __float22bfloat162_rn(make_float2(a, b));
    return v.u;
}

// ---------------------------------------------------------------------------
// Grid barrier v2b: regular-launch-safe, graph-capture-safe, and CHEAP.
// R4 lesson (626us, VALUBusy 5.4%): ACQUIRE polls emit buffer_inv (full
// L1+L2 invalidate) PER ITERATION; 512 pollers thrash every cache on chip.
// v2: poll with RELAXED + SYSTEM scope => coherence-point bypass load, NO
// cache maintenance per iteration.  Exactly one RELEASE fence before the
// arrival add and one ACQUIRE fence after the wait, thread 0 only
// (__syncthreads has already drained all waves' stores to L2: s_waitcnt
// vmcnt(0) precedes s_barrier).  R5 fix: __hip_atomic_fence doesn't exist
// in these headers -> use __builtin_amdgcn_fence(order, "agent").
// Ticket scheme: target=(t/64+1)*64 per 64-block shard -> self-consistent
// across graph replays with no reset.  8 shards, 128 B apart.
// Deadlock-safe by construction: __launch_bounds__(512,4) => VGPR<=128 =>
// 2 blocks/CU x 256 CU = 512 co-resident blocks = the whole grid.
// ---------------------------------------------------------------------------
__device__ unsigned long long g_bar[3][8][16];   // [barrier][shard][pad 128B]

__device__ __forceinline__ void grid_barrier(int b) {
    __syncthreads();   // all waves' stores drained (vmcnt0 before s_barrier)
    if (threadIdx.x == 0) {
        // release: single L2 writeback -> our phase stores visible device-wide
        __builtin_amdgcn_fence(__ATOMIC_RELEASE, "agent");
        const int s = blockIdx.x & 7;
        unsigned long long t = __hip_atomic_fetch_add(
            &g_bar[b][s][0], 1ull, __ATOMIC_RELAXED, __HIP_MEMORY_SCOPE_AGENT);
        const unsigned long long tgt = (t >> 6) * 64ull + 64ull;  // epoch+1
        #pragma unroll 1
        for (int ss = 0; ss < 8; ss++) {
            while (__hip_atomic_load(&g_bar[b][ss][0],
                       __ATOMIC_RELAXED, __HIP_MEMORY_SCOPE_SYSTEM) < tgt) {
                __builtin_amdgcn_s_sleep(2);
            }
        }
        // acquire: single L1+L2 invalidate -> see other XCDs' stores
        __builtin_amdgcn_fence(__ATOMIC_ACQUIRE, "agent");
    }
    __syncthreads();
}

// ---------------------------------------------------------------------------
// B-fragment table layout (consumed by mfma_f32_16x16x32_bf16):
//   HB[k][c][lane] : uint4;  lane=(q=lane>>4, n=lane&15)
//   dword t packs rows j=c*32+q*8+2t, +2t+1 of column n:
//   n<F -> bf16(h[j][n]); n==F -> 1.0 (denominator column); n>F -> 0.
// ---------------------------------------------------------------------------

struct SharedBufs {
    float F2s[1024];       // f2[k] (4 KB)
    float XPa[8][16][5];   // FUSE: attn output xo
    float XPb[8][16][9];   // FUSE: projected hv / !FUSE: xo tile
    float YPs[8][64];      // !FUSE: per-wave fc1 partials
    float hrow[128 * 4];   // P0 proj row-stage
    float ybuf[FC1];       // P3 fc1 activations
};  // ~15.7 KB; 2 blocks/CU -> 31 KB/CU, far under 160 KB

// ---------------------------------------------------------------------------
// Attention phase (instruction-identical main loop to the verified R2 kernel).
// FUSE (layer 1): epilogue computes layer-2 projection AND writes the HB2
// fragment table directly (wave-local LDS transpose), plus f12/f22.
// !FUSE (layer 2): epilogue computes per-wave fc1 partials over its 16x8
// output tile; block-reduces; writes race-free slot yp[blockIdx.x*64+c].
// ---------------------------------------------------------------------------
template <int F, bool FUSE>
__device__ __forceinline__ void attn_phase(
        const unsigned long long* __restrict__ maskM,  // [N][16] row-major
        const uint4* __restrict__ HBin,  // [K][32][64] B-frags
        const float* __restrict__ f1,    // [K,N]  (x log2e)
        const float* __restrict__ f2,    // [K,N]  (x log2e)
        const float* __restrict__ W2,    // [4,8]  (FUSE only)
        const float* __restrict__ a2,    // [16]   (FUSE only)
        const float* __restrict__ fc1w,  // [8192,54] (!FUSE only)
        uint4* __restrict__ HBout,       // FUSE: HB2 table
        float* __restrict__ yp,          // !FUSE: fc1 partial slots [512][64]
        float* __restrict__ o_f1,        // FUSE: f12 (x log2e)
        float* __restrict__ o_f2,        // FUSE: f22 (x log2e)
        SharedBufs& S) {
    const int tid  = threadIdx.x;
    const int lane = tid & 63;
    const int wv   = tid >> 6;
    const int quad = lane >> 4;
    const int n16  = lane & 15;
    const int k    = blockIdx.x >> 3;

    if (tid < 256)
        ((float4*)S.F2s)[tid] = ((const float4*)(f2 + k * N))[tid];
    __syncthreads();

    const int itile = (blockIdx.x & 7) * 8 + wv;     // 0..63
    const int ibase = itile * 16;
    const int irow  = ibase + n16;                   // this lane's P row
    const float f1v = f1[k * N + irow];
    const uint4* mrow = (const uint4*)((const char*)maskM + (size_t)irow * 128);
    const uint4* HBk  = HBin + (size_t)k * 2048;

    f32x4 acc = {0.f, 0.f, 0.f, 0.f};
    union { bf16x8 v; uint u[4]; } af;
    union { bf16x8 v; uint4 q; }  bfrag;

    #pragma unroll 2
    for (int g = 0; g < 8; g++) {
        const uint4 Mg = mrow[g];                    // 4 chunks of mask bits
        #pragma unroll
        for (int cc = 0; cc < 4; cc++) {
            const int c = g * 4 + cc;
            const uint mdw = (cc == 0) ? Mg.x : (cc == 1) ? Mg.y
                           : (cc == 2) ? Mg.z : Mg.w;
            const uint mb  = (mdw >> (quad * 8)) & 0xffu;  // 8 bits, this lane
            float4 fa = *(const float4*)(S.F2s + c * 32 + quad * 8);
            float4 fb = *(const float4*)(S.F2s + c * 32 + quad * 8 + 4);
            bfrag.q = HBk[c * 64 + lane];            // coalesced VMEM (L2)
            float f2e[8] = {fa.x, fa.y, fa.z, fa.w, fb.x, fb.y, fb.z, fb.w};
            float pv[8];
            #pragma unroll
            for (int jj = 0; jj < 8; jj++) {
                float x = f1v + f2e[jj];
                float e = fmaxf(x, ALPHA_F * x);     // leaky (log2-scaled)
                float p = fast_exp2(e);
                pv[jj] = (mb & (1u << jj)) ? p : 0.f;  // mask -> exact 0
            }
            #pragma unroll
            for (int pr = 0; pr < 4; pr++)
                af.u[pr] = pk_bf16(pv[2 * pr], pv[2 * pr + 1]);
            acc = __builtin_amdgcn_mfma_f32_16x16x32_bf16(af.v, bfrag.v, acc, 0, 0, 0);
        }
    }

    // ---- epilogue: C[m][n]: n=lane&15, m=quad*4+reg; denom in col n==F ----
    #pragma unroll
    for (int r = 0; r < 4; r++) {
        float den = __shfl(acc[r], (lane & 48) + F);
        float inv = (den > 0.f) ? 1.f / den : 0.f;
        float xo  = fmaxf(acc[r] * inv, 0.f);        // relu
        int m = quad * 4 + r;
        if constexpr (FUSE) {
            if (n16 < F) S.XPa[wv][m][n16] = xo;
        } else {
            if (n16 < F) S.XPb[wv][m][n16] = xo;     // wave-local stage
        }
    }

    if constexpr (FUSE) {
        __syncthreads();
        if (lane < 16) {
            const int m = lane;
            float x0 = S.XPa[wv][m][0], x1 = S.XPa[wv][m][1];
            float x2v = S.XPa[wv][m][2], x3 = S.XPa[wv][m][3];
            float hv[DOUT];
            #pragma unroll
            for (int f = 0; f < DOUT; f++) {
                hv[f] = x0 * W2[f]      + x1 * W2[8 + f]
                      + x2v * W2[16 + f] + x3 * W2[24 + f];
            }
            float t1 = 0.f, t2 = 0.f;
            #pragma unroll
            for (int f = 0; f < DOUT; f++) { t1 += hv[f] * a2[f]; t2 += hv[f] * a2[DOUT + f]; }
            const int row = k * N + ibase + m;
            o_f1[row] = t1 * LOG2E_F;
            o_f2[row] = t2 * LOG2E_F;
            #pragma unroll
            for (int f = 0; f < DOUT; f++) S.XPb[wv][m][f] = hv[f];
        }
        __syncthreads();
        if (lane < 32) {
            const int c2    = ibase >> 5;
            const int qhalf = (ibase >> 4) & 1;
            const int ql    = lane >> 4;
            const int n     = lane & 15;
            const int q     = qhalf * 2 + ql;
            uint4 dw;
            if (n < DOUT) {
                dw.x = pk_bf16(S.XPb[wv][ql * 8 + 0][n], S.XPb[wv][ql * 8 + 1][n]);
                dw.y = pk_bf16(S.XPb[wv][ql * 8 + 2][n], S.XPb[wv][ql * 8 + 3][n]);
                dw.z = pk_bf16(S.XPb[wv][ql * 8 + 4][n], S.XPb[wv][ql * 8 + 5][n]);
                dw.w = pk_bf16(S.XPb[wv][ql * 8 + 6][n], S.XPb[wv][ql * 8 + 7][n]);
            } else if (n == DOUT) {
                dw = make_uint4(0x3f803f80u, 0x3f803f80u, 0x3f803f80u, 0x3f803f80u);
            } else {
                dw = make_uint4(0u, 0u, 0u, 0u);
            }
            HBout[(size_t)k * 2048 + c2 * 64 + q * 16 + n] = dw;
        }
    } else {
        // ---- fused fc1: per-wave partial over this wave's 128 x2-columns ----
        // x2[k][m] for m = ibase*8 + mm, mm = lr*8 + f, lives in XPb[wv][lr][f]
        // (wave-local LDS: same wave wrote it, lgkmcnt ordering suffices).
        const int ceff = (lane < FC1) ? lane : 0;    // c = lane (54 active)
        const float* wb = fc1w + (size_t)ibase * DOUT * FC1;
        float pacc = 0.f;
        #pragma unroll 8
        for (int mm = 0; mm < 128; mm++) {
            float xv = S.XPb[wv][mm >> 3][mm & 7];   // wave-uniform broadcast
            pacc = fmaf(xv, wb[(size_t)mm * FC1 + ceff], pacc);
        }
        S.YPs[wv][lane] = pacc;
        __syncthreads();
        if (tid < 64) {
            float s = 0.f;
            #pragma unroll
            for (int w = 0; w < 8; w++) s += S.YPs[w][tid];
            yp[blockIdx.x * 64 + tid] = s;           // race-free slot write
        }
    }
}

// ---------------------------------------------------------------------------
// Mega kernel (regular launch + hand-rolled grid barrier):
// 512 blocks x 512 threads (= exactly 2 co-resident blocks/CU), 4 phases.
//  P0: mask pack (4 units/wave over all blocks) + gat1 proj of 128 rows/block
//      -> HB1 frags + f11/f21
//  P1: attn layer 1 (FUSE)  -> HB2 + f12/f22
//  P2: attn layer 2 + fused fc1 partials -> yp slots
//  P3: blocks 0..127: reduce yp + bias + relu -> out GEMV
// ---------------------------------------------------------------------------
__global__ __launch_bounds__(512, 4) void mega_kernel(
        const int* __restrict__ adj, unsigned long long* __restrict__ maskM,
        const float* __restrict__ X, const float* __restrict__ W1,
        const float* __restrict__ a1,
        uint4* __restrict__ HB1, float* __restrict__ f11, float* __restrict__ f21,
        const float* __restrict__ W2, const float* __restrict__ a2,
        const float* __restrict__ fc1w,
        uint4* __restrict__ HB2, float* __restrict__ f12, float* __restrict__ f22,
        float* __restrict__ yp,
        const float* __restrict__ fc1b, const float* __restrict__ outw,
        const float* __restrict__ outb, float* __restrict__ out) {
    __shared__ SharedBufs S;
    const int tid  = threadIdx.x;
    const int lane = tid & 63;
    const int wv   = tid >> 6;
    const int bid  = blockIdx.x;

    // ---- P0a: adjacency mask pack (16384 (i,jw) units; 4 per wave) ----
    {
        int g = bid * 8 + wv;              // 0..4095
        #pragma unroll
        for (int uu = 0; uu < 4; uu++) {
            int u = g * 4 + uu;            // 0..16383
            int jw = u >> 10;              // 0..15
            int i  = u & 1023;
            int v = adj[i * N + (jw << 6) + lane];    // coalesced 256B/wave
            unsigned long long m = __ballot(v > 0);   // bit lane = adj>0
            if (lane == 0) maskM[i * 16 + jw] = m;    // row-major
        }
    }

    // ---- P0b: gat1 proj, 128 rows per block -> f11/f21 + HB1 frags ----
    {
        const int k  = bid >> 3;
        const int j0 = (bid & 7) << 7;     // 0,128,...,896
        if (tid < 128) {
            const int idx = k * N + j0 + tid;
            const float4* x4 = (const float4*)(X + (size_t)idx * DIN);
            float hv_[H1] = {0.f, 0.f, 0.f, 0.f};
            #pragma unroll
            for (int q = 0; q < 4; q++) {
                float4 xv = x4[q];
                #pragma unroll
                for (int f = 0; f < H1; f++) {
                    hv_[f] += xv.x * W1[(q * 4 + 0) * H1 + f] + xv.y * W1[(q * 4 + 1) * H1 + f]
                            + xv.z * W1[(q * 4 + 2) * H1 + f] + xv.w * W1[(q * 4 + 3) * H1 + f];
                }
            }
            float s1 = 0.f, s2 = 0.f;
            #pragma unroll
            for (int f = 0; f < H1; f++) { s1 += hv_[f] * a1[f]; s2 += hv_[f] * a1[H1 + f]; }
            f11[idx] = s1 * LOG2E_F;
            f21[idx] = s2 * LOG2E_F;
            #pragma unroll
            for (int f = 0; f < H1; f++) S.hrow[tid * 4 + f] = hv_[f];
        }
        __syncthreads();
        if (tid < 256) {                   // 4 chunk-locals x 64 lanes
            int cl = tid >> 6, l = tid & 63, q = (l >> 4), n = l & 15;
            uint4 dw;
            if (n < H1) {
                const float* hp = S.hrow + (cl * 32 + q * 8) * 4 + n;
                dw.x = pk_bf16(hp[0],  hp[4]);
                dw.y = pk_bf16(hp[8],  hp[12]);
                dw.z = pk_bf16(hp[16], hp[20]);
                dw.w = pk_bf16(hp[24], hp[28]);
            } else if (n == H1) {
                dw = make_uint4(0x3f803f80u, 0x3f803f80u, 0x3f803f80u, 0x3f803f80u);
            } else {
                dw = make_uint4(0u, 0u, 0u, 0u);
            }
            HB1[(size_t)k * 2048 + ((j0 >> 5) + cl) * 64 + l] = dw;
        }
    }

    grid_barrier(0);

    // ---- P1: attention layer 1 (FUSE) ----
    attn_phase<H1, true>(maskM, HB1, f11, f21, W2, a2, nullptr,
                         HB2, nullptr, f12, f22, S);

    grid_barrier(1);

    // ---- P2: attention layer 2 + fused fc1 partials ----
    attn_phase<DOUT, false>(maskM, HB2, f12, f22, nullptr, nullptr, fc1w,
                            nullptr, yp, nullptr, nullptr, S);

    grid_barrier(2);

    // ---- P3: fc2 on blocks 0..127 (k = bid>>1, n-half = bid&1) ----
    if (bid < 128) {
        const int k  = bid >> 1;
        const int nh = bid & 1;
        if (tid < FC1) {
            float s = fc1b[tid];
            #pragma unroll
            for (int sl = 0; sl < 8; sl++) s += yp[((k << 3) + sl) * 64 + tid];
            S.ybuf[tid] = fmaxf(s, 0.f);   // bias + relu
        }
        __syncthreads();
        const int n = (nh << 9) + tid;     // 0..1023
        float s = outb[n];
        #pragma unroll 6
        for (int cc = 0; cc < FC1; cc++)
            s += S.ybuf[cc] * outw[(size_t)cc * N + n];
        out[(size_t)k * N + n] = s;
    }
}

// ---------------------------------------------------------------------------
extern "C" void kernel_launch(void* const* d_in, const int* in_sizes, int n_in,
                              void* d_out, int out_size, void* d_ws, size_t ws_size,
                              hipStream_t stream) {
    const float* X     = (const float*)d_in[0];
    const int*   adj   = (const int*)  d_in[1];
    const float* W1    = (const float*)d_in[2];
    const float* a1    = (const float*)d_in[3];
    const float* W2    = (const float*)d_in[4];
    const float* a2    = (const float*)d_in[5];
    const float* fc1w  = (const float*)d_in[6];
    const float* fc1b  = (const float*)d_in[7];
    const float* outw  = (const float*)d_in[8];
    const float* outb  = (const float*)d_in[9];
    float* out = (float*)d_out;

    // Workspace layout (floats); ~5.5 MB total
    float* ws  = (float*)d_ws;
    float* f11 = ws;                       // 65536
    float* f21 = f11 + 65536;              // 65536
    float* f12 = f21 + 65536;              // 65536
    float* f22 = f12 + 65536;              // 65536
    float* yp  = f22 + 65536;              // 32768 (512 slots x 64)
    unsigned long long* mM = (unsigned long long*)(yp + 32768);    // 16384 u64
    uint4* HB1 = (uint4*)(yp + 32768 + 32768);                     // 131072 u4
    uint4* HB2 = HB1 + 131072;                                     // 131072 u4

    mega_kernel<<<dim3(512), dim3(512), 0, stream>>>(
        adj, mM, X, W1, a1, HB1, f11, f21, W2, a2, fc1w,
        HB2, f12, f22, yp, fc1b, outw, outb, out);
}